// Round 5
// baseline (197.309 us; speedup 1.0000x reference)
//
#include <hip/hip_runtime.h>
#include <stdint.h>

typedef float    f32x4 __attribute__((ext_vector_type(4)));
typedef short    s16x8 __attribute__((ext_vector_type(8)));
typedef short    s16x4 __attribute__((ext_vector_type(4)));
typedef unsigned short u16;
typedef uint32_t u32;

#define DEVINL __device__ __forceinline__
#define CFENCE asm volatile("" ::: "memory")

DEVINL float bf2f(u16 u) { union { u32 i; float f; } x; x.i = ((u32)u) << 16; return x.f; }
DEVINL u16 f2bf(float f) {
  union { float f; u32 i; } x; x.f = f;
  u32 i = x.i;
  return (u16)((i + 0x7FFFu + ((i >> 16) & 1u)) >> 16);  // RNE
}

DEVINL void gload16(const void* g, void* l) {
  __builtin_amdgcn_global_load_lds((const __attribute__((address_space(1))) void*)g,
                                   (__attribute__((address_space(3))) void*)l,
                                   16, 0, 0);
}

// ---------------------------------------------- W[K][N] fp32 -> Wt[N][K] bf16
__global__ __launch_bounds__(256) void k_transpose_bf16(const float* __restrict__ W,
                                                        u16* __restrict__ Wt, int K, int N) {
  __shared__ __align__(16) float t[64][65];
  int nb = N >> 6;
  int tn = blockIdx.x % nb, tk = blockIdx.x / nb;
  int n0 = tn << 6, k0 = tk << 6;
  int tid = threadIdx.x;
  int cr = tid >> 4, cc = (tid & 15) << 2;
#pragma unroll
  for (int i = 0; i < 4; i++) {
    int r = cr + (i << 4);
    f32x4 v = *(const f32x4*)(W + (size_t)(k0 + r) * N + n0 + cc);
    t[r][cc] = v[0]; t[r][cc + 1] = v[1]; t[r][cc + 2] = v[2]; t[r][cc + 3] = v[3];
  }
  __syncthreads();
#pragma unroll
  for (int i = 0; i < 4; i++) {
    int nn = cr + (i << 4);
    s16x4 o;
    o[0] = (short)f2bf(t[cc    ][nn]);
    o[1] = (short)f2bf(t[cc + 1][nn]);
    o[2] = (short)f2bf(t[cc + 2][nn]);
    o[3] = (short)f2bf(t[cc + 3][nn]);
    *(s16x4*)(Wt + (size_t)(n0 + nn) * K + k0 + cc) = o;
  }
}

// ------------------------------------------------------------------ GEMM1
// qkv = x(fp32!) @ WqkvT, fp32->bf16 cvt FUSED into reg-staging (T14 split:
// loads at tile top, cvt+ds_write after MFMA cluster). 256x256 tile, 8 waves
// (2Mx4N), BK=32, 2 LDS bufs (64 KiB), ONE barrier per tile. Both-sides
// swizzle ch^((row>>1)&3). Epilogue: phi on q/k, scatter [bh][n][d].
__global__ __launch_bounds__(512, 1) void k_gemm1(
    const float* __restrict__ A, const u16* __restrict__ Bt, int nbn,
    u16* __restrict__ qph, u16* __restrict__ kph, u16* __restrict__ vv) {
  __shared__ __align__(16) u16 lsA[2][256 * 32];
  __shared__ __align__(16) u16 lsB[2][256 * 32];

  int nwg = gridDim.x, bx = blockIdx.x;
  int o = (bx & 7) * (nwg >> 3) + (bx >> 3);   // XCD swizzle (nwg%8==0)
  int bm = o / nbn, bn = o % nbn;
  int m0 = bm << 8, n0 = bn << 8;
  int tid = threadIdx.x, w = tid >> 6, lane = tid & 63;
  int lnlo = lane & 15, lnhi = lane >> 4;
  int wr = w >> 2, wc = w & 3;                  // 2 x 4 wave grid

  // staging addrs: tile = 256 rows x 4 chunks(16B bf16 = 32B fp32 for A);
  // thread owns chunks tid, tid+512; global chunk pre-swizzled (involution
  // matches read side), LDS dest linear.
  const float* gAf[2]; const u16* gBp[2]; int ldst[2];
#pragma unroll
  for (int i = 0; i < 2; i++) {
    int c = tid + i * 512, row = c >> 2, ch = c & 3;
    int gch = ch ^ ((row >> 1) & 3);
    gAf[i] = A + (size_t)(m0 + row) * 512 + gch * 8;
    gBp[i] = Bt + (size_t)(n0 + row) * 512 + gch * 8;
    ldst[i] = c * 8;
  }
  int offA[8], offB[4];
#pragma unroll
  for (int f = 0; f < 8; f++) { int r = wr * 128 + f * 16 + lnlo; offA[f] = r * 32 + (lnhi ^ ((r >> 1) & 3)) * 8; }
#pragma unroll
  for (int f = 0; f < 4; f++) { int r = wc * 64 + f * 16 + lnlo; offB[f] = r * 32 + (lnhi ^ ((r >> 1) & 3)) * 8; }

  f32x4 rA[2][2]; s16x8 rB[2];
  f32x4 acc[8][4] = {};

  // prologue: load+write tile 0 into buf 0
#pragma unroll
  for (int i = 0; i < 2; i++) {
    const float* s = gAf[i];
    rA[i][0] = *(const f32x4*)s; rA[i][1] = *(const f32x4*)(s + 4);
    rB[i] = *(const s16x8*)gBp[i];
  }
#pragma unroll
  for (int i = 0; i < 2; i++) {
    s16x8 oo;
#pragma unroll
    for (int j = 0; j < 4; j++) { oo[j] = (short)f2bf(rA[i][0][j]); oo[4 + j] = (short)f2bf(rA[i][1][j]); }
    *(s16x8*)&lsA[0][ldst[i]] = oo;
    *(s16x8*)&lsB[0][ldst[i]] = rB[i];
  }
  asm volatile("s_waitcnt lgkmcnt(0)" ::: "memory");
  __builtin_amdgcn_s_barrier();
  CFENCE;

#pragma unroll
  for (int t = 0; t < 16; t++) {
    const int par = t & 1;
    // issue next tile's global loads FIRST (latency hides under MFMA)
    if (t < 15) {
      int k1 = (t + 1) * 32;
#pragma unroll
      for (int i = 0; i < 2; i++) {
        const float* s = gAf[i] + k1;
        rA[i][0] = *(const f32x4*)s; rA[i][1] = *(const f32x4*)(s + 4);
        rB[i] = *(const s16x8*)(gBp[i] + k1);
      }
    }
    CFENCE;   // pin load issue before LDS traffic
    s16x8 af[8], bf[4];
#pragma unroll
    for (int f = 0; f < 4; f++) bf[f] = *(const s16x8*)&lsB[par][offB[f]];
#pragma unroll
    for (int f = 0; f < 8; f++) af[f] = *(const s16x8*)&lsA[par][offA[f]];
    __builtin_amdgcn_s_setprio(1);
#pragma unroll
    for (int mf = 0; mf < 8; mf++)
#pragma unroll
      for (int nf = 0; nf < 4; nf++)
        acc[mf][nf] = __builtin_amdgcn_mfma_f32_16x16x32_bf16(af[mf], bf[nf], acc[mf][nf], 0, 0, 0);
    __builtin_amdgcn_s_setprio(0);
    if (t < 15) {
      // cvt + ds_write next tile into ~par (freed by previous barrier)
#pragma unroll
      for (int i = 0; i < 2; i++) {
        s16x8 oo;
#pragma unroll
        for (int j = 0; j < 4; j++) { oo[j] = (short)f2bf(rA[i][0][j]); oo[4 + j] = (short)f2bf(rA[i][1][j]); }
        *(s16x8*)&lsA[par ^ 1][ldst[i]] = oo;
        *(s16x8*)&lsB[par ^ 1][ldst[i]] = rB[i];
      }
      asm volatile("s_waitcnt lgkmcnt(0)" ::: "memory");  // writes visible
      CFENCE;
      __builtin_amdgcn_s_barrier();
      CFENCE;
    }
  }

  int gmB = m0 + wr * 128;
  int gnB = n0 + wc * 64;
#pragma unroll
  for (int mf = 0; mf < 8; mf++) {
#pragma unroll
    for (int nf = 0; nf < 4; nf++) {
      int col = gnB + nf * 16 + lnlo;
      int sec = col >> 9;
      int hh = (col >> 6) & 7;
      int dd = col & 63;
      u16* dst = (sec == 0) ? qph : ((sec == 1) ? kph : vv);
#pragma unroll
      for (int r = 0; r < 4; r++) {
        int rowm = gmB + mf * 16 + lnhi * 4 + r;
        float val = acc[mf][nf][r];
        if (sec < 2) val = (val > 0.f) ? (val + 1.f) : __expf(val);  // elu+1
        int bidx = rowm >> 12, tok = rowm & 4095;
        dst[(((size_t)(bidx * 8 + hh) * 4096 + tok) << 6) + dd] = f2bf(val);
      }
    }
  }
}

// ------------------------------------------------------------------- GEMM2
// out = y @ WoutT + b. r4 structure kept verbatim (bf16 A, gload_lds,
// BK=32, 3-deep bufs, counted vmcnt, 2 phases/tile).
template <int EPI>
__global__ __launch_bounds__(512, 1) void k_gemm(
    const u16* __restrict__ A, const u16* __restrict__ Bt,
    int nbn,
    u16* __restrict__ qph, u16* __restrict__ kph, u16* __restrict__ vv,
    float* __restrict__ out, const float* __restrict__ bias) {
  __shared__ __align__(16) u16 lsA[3][256 * 32];
  __shared__ __align__(16) u16 lsB[3][256 * 32];

  int nwg = gridDim.x;
  int bx = blockIdx.x;
  int o = (bx & 7) * (nwg >> 3) + (bx >> 3);
  int bm = o / nbn, bn = o % nbn;
  int m0 = bm << 8, n0 = bn << 8;
  int tid = threadIdx.x;
  int w = tid >> 6, lane = tid & 63;
  int lnlo = lane & 15, lnhi = lane >> 4;
  int wr = w >> 2, wc = w & 3;

  const u16* gAp[2]; const u16* gBp[2]; int ldst[2];
#pragma unroll
  for (int i = 0; i < 2; i++) {
    int c = tid + i * 512;
    int row = c >> 2, ch = c & 3;
    int gch = ch ^ ((row >> 1) & 3);
    gAp[i] = A + (size_t)(m0 + row) * 512 + gch * 8;
    gBp[i] = Bt + (size_t)(n0 + row) * 512 + gch * 8;
    ldst[i] = c * 8;
  }

  int offA[8], offB[4];
#pragma unroll
  for (int f = 0; f < 8; f++) {
    int r = wr * 128 + f * 16 + lnlo;
    offA[f] = r * 32 + (lnhi ^ ((r >> 1) & 3)) * 8;
  }
#pragma unroll
  for (int f = 0; f < 4; f++) {
    int r = wc * 64 + f * 16 + lnlo;
    offB[f] = r * 32 + (lnhi ^ ((r >> 1) & 3)) * 8;
  }

  f32x4 acc[8][4] = {};

#pragma unroll
  for (int i = 0; i < 2; i++) gload16(gAp[i], &lsA[0][ldst[i]]);
#pragma unroll
  for (int i = 0; i < 2; i++) gload16(gBp[i], &lsB[0][ldst[i]]);
#pragma unroll
  for (int i = 0; i < 2; i++) gload16(gAp[i] + 32, &lsA[1][ldst[i]]);
#pragma unroll
  for (int i = 0; i < 2; i++) gload16(gBp[i] + 32, &lsB[1][ldst[i]]);
  asm volatile("s_waitcnt vmcnt(4)" ::: "memory");
  __builtin_amdgcn_s_barrier();

#pragma unroll
  for (int t = 0; t < 16; t++) {
    int buf = t % 3;
    const u16* La = &lsA[buf][0];
    const u16* Lb = &lsB[buf][0];
    int k2 = (t + 2) * 32;
    int b2 = (t + 2) % 3;

    s16x8 bf[4], af[4];
#pragma unroll
    for (int f = 0; f < 4; f++) bf[f] = *(const s16x8*)(Lb + offB[f]);
#pragma unroll
    for (int f = 0; f < 4; f++) af[f] = *(const s16x8*)(La + offA[f]);
    if (t < 14) {
#pragma unroll
      for (int i = 0; i < 2; i++) gload16(gAp[i] + k2, &lsA[b2][ldst[i]]);
    }
    __builtin_amdgcn_s_barrier();
    __builtin_amdgcn_s_setprio(1);
#pragma unroll
    for (int mf = 0; mf < 4; mf++)
#pragma unroll
      for (int nf = 0; nf < 4; nf++)
        acc[mf][nf] = __builtin_amdgcn_mfma_f32_16x16x32_bf16(af[mf], bf[nf], acc[mf][nf], 0, 0, 0);
    __builtin_amdgcn_s_setprio(0);
    __builtin_amdgcn_s_barrier();

    s16x8 af2[4];
#pragma unroll
    for (int f = 0; f < 4; f++) af2[f] = *(const s16x8*)(La + offA[4 + f]);
    if (t < 14) {
#pragma unroll
      for (int i = 0; i < 2; i++) gload16(gBp[i] + k2, &lsB[b2][ldst[i]]);
    }
    __builtin_amdgcn_s_barrier();
    __builtin_amdgcn_s_setprio(1);
#pragma unroll
    for (int mf = 0; mf < 4; mf++)
#pragma unroll
      for (int nf = 0; nf < 4; nf++)
        acc[4 + mf][nf] = __builtin_amdgcn_mfma_f32_16x16x32_bf16(af2[mf], bf[nf], acc[4 + mf][nf], 0, 0, 0);
    __builtin_amdgcn_s_setprio(0);
    if (t <= 13)      asm volatile("s_waitcnt vmcnt(4)" ::: "memory");
    else if (t == 14) asm volatile("s_waitcnt vmcnt(0)" ::: "memory");
    if (t < 15) __builtin_amdgcn_s_barrier();
  }

  int gmB = m0 + wr * 128;
  int gnB = n0 + wc * 64;
#pragma unroll
  for (int mf = 0; mf < 8; mf++) {
#pragma unroll
    for (int nf = 0; nf < 4; nf++) {
      int col = gnB + nf * 16 + lnlo;
      float bv = bias[col];
#pragma unroll
      for (int r = 0; r < 4; r++) {
        int rowm = gmB + mf * 16 + lnhi * 4 + r;
        out[(size_t)rowm * 512 + col] = acc[mf][nf][r] + bv;
      }
    }
  }
}

// -------------------------------------------- KV[d][e] partials + Ksum[d]
// grid = 64 bh * 16 k-splits; 256 tokens per block; 4x4 register tile/thread;
// tk-blocked x4 (8 ds_read_b128/thread/step instead of 32 -> VALU-bound).
__global__ __launch_bounds__(256) void k_kv(const u16* __restrict__ kphi,
                                            const u16* __restrict__ vbuf,
                                            float* __restrict__ kvpart,
                                            float* __restrict__ kspart) {
  __shared__ __align__(16) float kf[16][64];
  __shared__ __align__(16) float vf[16][64];
  int bx = blockIdx.x;
  int bh = bx >> 4, ck = bx & 15;
  int tid = threadIdx.x;
  size_t base = ((size_t)bh * 4096 + ck * 256) * 64;
  float acc[4][4] = {};
  float ks[4] = {0.f, 0.f, 0.f, 0.f};
  int dq = tid >> 4, eq = tid & 15;
  int d0 = dq * 4, e0 = eq * 4;
  int half = tid >> 7;
  int t2 = tid & 127;
  int srow = t2 >> 3, sch = t2 & 7;

  for (int step = 0; step < 16; step++) {
    {
      const u16* src = (half ? vbuf : kphi) + base + (size_t)(step * 16 + srow) * 64 + sch * 8;
      s16x8 v8 = *(const s16x8*)src;
      float* dst = (half ? &vf[0][0] : &kf[0][0]) + srow * 64 + sch * 8;
      f32x4 lo = {bf2f((u16)v8[0]), bf2f((u16)v8[1]), bf2f((u16)v8[2]), bf2f((u16)v8[3])};
      f32x4 hi = {bf2f((u16)v8[4]), bf2f((u16)v8[5]), bf2f((u16)v8[6]), bf2f((u16)v8[7])};
      *(f32x4*)dst = lo;
      *(f32x4*)(dst + 4) = hi;
    }
    __syncthreads();
#pragma unroll
    for (int tkb = 0; tkb < 4; tkb++) {
      f32x4 kq[4], vq[4];
#pragma unroll
      for (int j = 0; j < 4; j++) {
        kq[j] = *(const f32x4*)&kf[tkb * 4 + j][d0];
        vq[j] = *(const f32x4*)&vf[tkb * 4 + j][e0];
      }
#pragma unroll
      for (int j = 0; j < 4; j++) {
#pragma unroll
        for (int i = 0; i < 4; i++)
#pragma unroll
          for (int l = 0; l < 4; l++) acc[i][l] += kq[j][i] * vq[j][l];
        if (eq == 0) {
#pragma unroll
          for (int i = 0; i < 4; i++) ks[i] += kq[j][i];
        }
      }
    }
    __syncthreads();
  }
  size_t pb = (size_t)(bh * 16 + ck) * 4096;
#pragma unroll
  for (int i = 0; i < 4; i++) {
    f32x4 o = {acc[i][0], acc[i][1], acc[i][2], acc[i][3]};
    *(f32x4*)(kvpart + pb + (size_t)(d0 + i) * 64 + e0) = o;
  }
  if (eq == 0) {
    f32x4 o = {ks[0], ks[1], ks[2], ks[3]};
    *(f32x4*)(kspart + (size_t)(bh * 16 + ck) * 64 + d0) = o;
  }
}

// --------------------- reduce partials -> KVt[e][d] bf16 (pre-swizzled) + Ksum
__global__ __launch_bounds__(256) void k_kvred(const float* __restrict__ kvpart,
                                               const float* __restrict__ kspart,
                                               u16* __restrict__ kvt_sw,
                                               float* __restrict__ ksum) {
  int bh = blockIdx.x;
  int tid = threadIdx.x;
  int e = tid >> 2, d0 = (tid & 3) * 16;
  size_t pb = (size_t)bh * 16 * 4096;
#pragma unroll
  for (int dd = 0; dd < 16; dd++) {
    int d = d0 + dd;
    float s = 0.f;
#pragma unroll
    for (int c = 0; c < 16; c++) s += kvpart[pb + (size_t)c * 4096 + d * 64 + e];
    int chs = (d >> 3) ^ (e & 7);
    kvt_sw[((size_t)bh * 64 + e) * 64 + chs * 8 + (d & 7)] = f2bf(s);
  }
  if (tid < 64) {
    float s = 0.f;
#pragma unroll
    for (int c = 0; c < 16; c++) s += kspart[(size_t)bh * 1024 + c * 64 + tid];
    ksum[bh * 64 + tid] = s;
  }
}

// ------------------------- y[tok][h*64+e] = (q_phi @ KV) / (q_phi . Ksum + eps)
__global__ __launch_bounds__(256, 2) void k_attnout(const u16* __restrict__ qphi,
                                                    const u16* __restrict__ kvt_sw,
                                                    const float* __restrict__ ksum,
                                                    u16* __restrict__ y) {
  __shared__ __align__(16) u16 qa[256 * 64];
  __shared__ __align__(16) u16 bb[64 * 64];
  __shared__ float ksl[64];
  __shared__ float rdnl[256];
  int bx = blockIdx.x;
  int bh = bx >> 4, tch = bx & 15;
  int b = bh >> 3, hh = bh & 7;
  int tid = threadIdx.x, w = tid >> 6, lane = tid & 63;
  int lnlo = lane & 15, lnhi = lane >> 4;
  size_t qbase = ((size_t)bh * 4096 + tch * 256) * 64;

#pragma unroll
  for (int i = 0; i < 8; i++) {
    int c = i * 256 + tid;
    int row = c >> 3, ch = c & 7;
    int gcol = (ch ^ (row & 7)) << 3;
    gload16(qphi + qbase + (size_t)row * 64 + gcol, &qa[c * 8]);
  }
#pragma unroll
  for (int i = 0; i < 2; i++) {
    int c = i * 256 + tid;
    gload16(kvt_sw + (size_t)bh * 4096 + c * 8, &bb[c * 8]);
  }
  if (tid < 64) ksl[tid] = ksum[bh * 64 + tid];
  __syncthreads();

  {
    float den = 0.f;
#pragma unroll
    for (int ch = 0; ch < 8; ch++) {
      s16x8 v8 = *(const s16x8*)&qa[tid * 64 + ((ch ^ (tid & 7)) << 3)];
#pragma unroll
      for (int j = 0; j < 8; j++) den += bf2f((u16)v8[j]) * ksl[ch * 8 + j];
    }
    rdnl[tid] = 1.f / (den + 1e-6f);
  }
  __syncthreads();

  f32x4 acc[4][4] = {};
#pragma unroll
  for (int kk = 0; kk < 2; kk++) {
    s16x8 af[4], bfr[4];
#pragma unroll
    for (int f = 0; f < 4; f++) {
      int ra = w * 64 + f * 16 + lnlo;
      int ca = (kk * 4 + lnhi) ^ (ra & 7);
      af[f] = *(const s16x8*)&qa[ra * 64 + ca * 8];
      int rb = f * 16 + lnlo;
      int cb = (kk * 4 + lnhi) ^ (rb & 7);
      bfr[f] = *(const s16x8*)&bb[rb * 64 + cb * 8];
    }
#pragma unroll
    for (int mf = 0; mf < 4; mf++)
#pragma unroll
      for (int nf = 0; nf < 4; nf++)
        acc[mf][nf] = __builtin_amdgcn_mfma_f32_16x16x32_bf16(af[mf], bfr[nf], acc[mf][nf], 0, 0, 0);
  }

  size_t yrow0 = (size_t)b * 4096 + tch * 256;
#pragma unroll
  for (int mf = 0; mf < 4; mf++) {
#pragma unroll
    for (int nf = 0; nf < 4; nf++) {
      int e = nf * 16 + lnlo;
#pragma unroll
      for (int r = 0; r < 4; r++) {
        int tl = w * 64 + mf * 16 + lnhi * 4 + r;
        float val = acc[mf][nf][r] * rdnl[tl];
        y[(yrow0 + tl) * 512 + hh * 64 + e] = f2bf(val);
      }
    }
  }
}

// ------------------------------------------------------------------ launch
#define OFF_Y      ((size_t)0)             // 33,554,432
#define OFF_WQKVT  ((size_t)33554432)      //  1,572,864
#define OFF_WOUTT  ((size_t)35127296)      //    524,288
#define OFF_QPHI   ((size_t)35651584)      // 33,554,432
#define OFF_KPHI   ((size_t)69206016)      // 33,554,432
#define OFF_VBUF   ((size_t)102760448)     // 33,554,432
#define OFF_KVPART ((size_t)136314880)     // 16,777,216
#define OFF_KSPART ((size_t)153092096)     //    262,144
#define OFF_KVT    ((size_t)153354240)     //    524,288
#define OFF_KSUM   ((size_t)153878528)     //     16,384

extern "C" void kernel_launch(void* const* d_in, const int* in_sizes, int n_in,
                              void* d_out, int out_size, void* d_ws, size_t ws_size,
                              hipStream_t stream) {
  const float* x    = (const float*)d_in[0];
  const float* Wqkv = (const float*)d_in[1];
  const float* Wout = (const float*)d_in[2];
  const float* bout = (const float*)d_in[3];
  float* out = (float*)d_out;
  char* ws = (char*)d_ws;

  u16* y      = (u16*)(ws + OFF_Y);
  u16* wqkvt  = (u16*)(ws + OFF_WQKVT);
  u16* woutt  = (u16*)(ws + OFF_WOUTT);
  u16* qphi   = (u16*)(ws + OFF_QPHI);
  u16* kphi   = (u16*)(ws + OFF_KPHI);
  u16* vbuf   = (u16*)(ws + OFF_VBUF);
  float* kvpart = (float*)(ws + OFF_KVPART);
  float* kspart = (float*)(ws + OFF_KSPART);
  u16* kvt_sw = (u16*)(ws + OFF_KVT);
  float* ksum = (float*)(ws + OFF_KSUM);

  k_transpose_bf16<<<(1536 / 64) * (512 / 64), 256, 0, stream>>>(Wqkv, wqkvt, 512, 1536);
  k_transpose_bf16<<<(512 / 64) * (512 / 64), 256, 0, stream>>>(Wout, woutt, 512, 512);

  // qkv = x @ Wqkv (fp32 A, fused cvt) + phi epilogue scatter
  k_gemm1<<<768, 512, 0, stream>>>(x, wqkvt, 6, qphi, kphi, vbuf);
  k_kv<<<64 * 16, 256, 0, stream>>>(kphi, vbuf, kvpart, kspart);
  k_kvred<<<64, 256, 0, stream>>>(kvpart, kspart, kvt_sw, ksum);
  k_attnout<<<64 * 16, 256, 0, stream>>>(qphi, kvt_sw, ksum, y);
  // out = y @ Wout + b
  k_gemm<1><<<256, 512, 0, stream>>>(y, woutt, 2, nullptr, nullptr, nullptr, out, bout);
}

// Round 6
// 196.508 us; speedup vs baseline: 1.0041x; 1.0041x over previous
//
#include <hip/hip_runtime.h>
#include <stdint.h>

typedef float    f32x4 __attribute__((ext_vector_type(4)));
typedef short    s16x8 __attribute__((ext_vector_type(8)));
typedef short    s16x4 __attribute__((ext_vector_type(4)));
typedef unsigned short u16;
typedef uint32_t u32;

#define DEVINL __device__ __forceinline__
#define CFENCE asm volatile("" ::: "memory")

DEVINL float bf2f(u16 u) { union { u32 i; float f; } x; x.i = ((u32)u) << 16; return x.f; }
DEVINL u16 f2bf(float f) {
  union { float f; u32 i; } x; x.f = f;
  u32 i = x.i;
  return (u16)((i + 0x7FFFu + ((i >> 16) & 1u)) >> 16);  // RNE
}

DEVINL void gload16(const void* g, void* l) {
  __builtin_amdgcn_global_load_lds((const __attribute__((address_space(1))) void*)g,
                                   (__attribute__((address_space(3))) void*)l,
                                   16, 0, 0);
}

// ---------------------------------------------------------------- conv x->bf16
__global__ __launch_bounds__(256) void k_conv_bf16(const float* __restrict__ x,
                                                   u16* __restrict__ xb, int n8) {
  int stride = gridDim.x * blockDim.x;
  for (int i = blockIdx.x * blockDim.x + threadIdx.x; i < n8; i += stride) {
    const f32x4* p = (const f32x4*)(x + (size_t)i * 8);
    f32x4 a = p[0], b = p[1];
    s16x8 o;
    o[0] = (short)f2bf(a[0]); o[1] = (short)f2bf(a[1]);
    o[2] = (short)f2bf(a[2]); o[3] = (short)f2bf(a[3]);
    o[4] = (short)f2bf(b[0]); o[5] = (short)f2bf(b[1]);
    o[6] = (short)f2bf(b[2]); o[7] = (short)f2bf(b[3]);
    *(s16x8*)(xb + (size_t)i * 8) = o;
  }
}

// ---------------------------------------------- W[K][N] fp32 -> Wt[N][K] bf16
__global__ __launch_bounds__(256) void k_transpose_bf16(const float* __restrict__ W,
                                                        u16* __restrict__ Wt, int K, int N) {
  __shared__ __align__(16) float t[64][65];
  int nb = N >> 6;
  int tn = blockIdx.x % nb, tk = blockIdx.x / nb;
  int n0 = tn << 6, k0 = tk << 6;
  int tid = threadIdx.x;
  int cr = tid >> 4, cc = (tid & 15) << 2;
#pragma unroll
  for (int i = 0; i < 4; i++) {
    int r = cr + (i << 4);
    f32x4 v = *(const f32x4*)(W + (size_t)(k0 + r) * N + n0 + cc);
    t[r][cc] = v[0]; t[r][cc + 1] = v[1]; t[r][cc + 2] = v[2]; t[r][cc + 3] = v[3];
  }
  __syncthreads();
#pragma unroll
  for (int i = 0; i < 4; i++) {
    int nn = cr + (i << 4);
    s16x4 o;
    o[0] = (short)f2bf(t[cc    ][nn]);
    o[1] = (short)f2bf(t[cc + 1][nn]);
    o[2] = (short)f2bf(t[cc + 2][nn]);
    o[3] = (short)f2bf(t[cc + 3][nn]);
    *(s16x4*)(Wt + (size_t)(n0 + nn) * K + k0 + cc) = o;
  }
}

// ------------------------------------------------------------------- GEMM
// C[M][N] = A[M][K=512] * Bt[N][K=512]^T, bf16 in / fp32 acc.
// B-DIRECT structure: Bt is L2-resident (<=1.5 MB) -> B-fragments read
// straight from global into VGPRs (double-buffered across the unrolled
// K-loop). Only A is LDS-staged (128x32 dbuf = 16 KB) via global_load_lds
// with both-sides 4-chunk swizzle. 128x256 tile, 256 threads (4 waves 1Mx4N,
// wave tile 128x64), TWO independent blocks/CU (launch_bounds(256,2)) so
// one block's LDS/VMEM work overlaps the other's MFMA clusters.
// Per tile: {stage A(t+1) (2 gload_lds) | prefetch B(t+1) (4 reg loads) |
//   8 ds_read_b128 A-frags | 32 MFMA (setprio) | vmcnt(4) | s_barrier}.
// vmcnt ledger: this tile issues 2 A-gloads then 4 B-loads (CFENCE-pinned
// order); prior B consumed by compiler-inserted waits before MFMA; so at
// vmcnt(4) the 2 oldest = this tile's A-gloads -> A(t+1) landed. Never 0.
// EPI 0: qkv epilogue (phi on q/k, scatter to [bh][n][d] bf16 bufs)
// EPI 1: out = val + bias, fp32
template <int EPI>
__global__ __launch_bounds__(256, 2) void k_gemm(
    const u16* __restrict__ A, const u16* __restrict__ Bt,
    int nbm,
    u16* __restrict__ qph, u16* __restrict__ kph, u16* __restrict__ vv,
    float* __restrict__ out, const float* __restrict__ bias) {
  __shared__ __align__(16) u16 lsA[2][128 * 32];

  int nwg = gridDim.x, bx = blockIdx.x;
  int o = (bx & 7) * (nwg >> 3) + (bx >> 3);   // XCD-contiguous chunks (nwg%8==0)
  int bn = o / nbm, bm = o % nbm;              // N-strip major: chunk shares B (L2)
  int m0 = bm << 7, n0 = bn << 8;
  int tid = threadIdx.x, w = tid >> 6, lane = tid & 63;
  int lnlo = lane & 15, lnhi = lane >> 4;

  // A staging: 128 rows x 4 chunks(16B); thread owns chunks tid, tid+256.
  // LDS dest linear; global chunk pre-swizzled ch^((row>>1)&3) (involution).
  const u16* gA0; const u16* gA1; int ldst0, ldst1;
  {
    int c = tid, row = c >> 2, ch = c & 3;
    gA0 = A + (size_t)(m0 + row) * 512 + (ch ^ ((row >> 1) & 3)) * 8;
    ldst0 = c * 8;
    c = tid + 256; row = c >> 2; ch = c & 3;
    gA1 = A + (size_t)(m0 + row) * 512 + (ch ^ ((row >> 1) & 3)) * 8;
    ldst1 = c * 8;
  }
  // B fragment pointers (global, per-lane): frag nf -> col n0+w*64+nf*16+lnlo
  const u16* gB[4];
#pragma unroll
  for (int nf = 0; nf < 4; nf++)
    gB[nf] = Bt + (size_t)(n0 + w * 64 + nf * 16 + lnlo) * 512 + lnhi * 8;
  // A fragment LDS offsets (u16 units), swizzled read side, row stride 32
  int offA[8];
#pragma unroll
  for (int mf = 0; mf < 8; mf++) {
    int r = mf * 16 + lnlo;
    offA[mf] = r * 32 + (lnhi ^ ((r >> 1) & 3)) * 8;
  }

  f32x4 acc[8][4] = {};
  s16x8 rB0[4], rB1[4];

  // prologue: stage A(0), prefetch B(0)
  gload16(gA0, &lsA[0][ldst0]);
  gload16(gA1, &lsA[0][ldst1]);
  CFENCE;
#pragma unroll
  for (int nf = 0; nf < 4; nf++) rB0[nf] = *(const s16x8*)gB[nf];
  CFENCE;
  asm volatile("s_waitcnt vmcnt(4)" ::: "memory");   // A(0) landed; B(0) flying
  __builtin_amdgcn_s_barrier();
  CFENCE;

  auto tile = [&](int t, s16x8 (&rcur)[4], s16x8 (&rnxt)[4]) {
    const int par = t & 1;
    if (t < 15) {
      int k1 = (t + 1) * 32;
      gload16(gA0 + k1, &lsA[par ^ 1][ldst0]);
      gload16(gA1 + k1, &lsA[par ^ 1][ldst1]);
      CFENCE;
#pragma unroll
      for (int nf = 0; nf < 4; nf++) rnxt[nf] = *(const s16x8*)(gB[nf] + k1);
      CFENCE;
    }
    s16x8 af[8];
#pragma unroll
    for (int mf = 0; mf < 8; mf++) af[mf] = *(const s16x8*)&lsA[par][offA[mf]];
    __builtin_amdgcn_s_setprio(1);
#pragma unroll
    for (int mf = 0; mf < 8; mf++)
#pragma unroll
      for (int nf = 0; nf < 4; nf++)
        acc[mf][nf] = __builtin_amdgcn_mfma_f32_16x16x32_bf16(af[mf], rcur[nf], acc[mf][nf], 0, 0, 0);
    __builtin_amdgcn_s_setprio(0);
    if (t < 15) {
      asm volatile("s_waitcnt vmcnt(4)" ::: "memory");  // A(t+1) landed
      __builtin_amdgcn_s_barrier();                      // par^1 free to read
      CFENCE;
    }
  };

#pragma unroll
  for (int t = 0; t < 16; t += 2) {
    tile(t, rB0, rB1);
    tile(t + 1, rB1, rB0);
  }

  int gnB = n0 + w * 64;
  if (EPI == 0) {
#pragma unroll
    for (int mf = 0; mf < 8; mf++) {
#pragma unroll
      for (int nf = 0; nf < 4; nf++) {
        int col = gnB + nf * 16 + lnlo;
        int sec = col >> 9;
        int hh = (col >> 6) & 7;
        int dd = col & 63;
        u16* dst = (sec == 0) ? qph : ((sec == 1) ? kph : vv);
#pragma unroll
        for (int r = 0; r < 4; r++) {
          int rowm = m0 + mf * 16 + lnhi * 4 + r;
          float val = acc[mf][nf][r];
          if (sec < 2) val = (val > 0.f) ? (val + 1.f) : __expf(val);  // elu+1
          int bidx = rowm >> 12, tok = rowm & 4095;
          dst[(((size_t)(bidx * 8 + hh) * 4096 + tok) << 6) + dd] = f2bf(val);
        }
      }
    }
  } else {
#pragma unroll
    for (int mf = 0; mf < 8; mf++) {
#pragma unroll
      for (int nf = 0; nf < 4; nf++) {
        int col = gnB + nf * 16 + lnlo;
        float bv = bias[col];
#pragma unroll
        for (int r = 0; r < 4; r++) {
          int rowm = m0 + mf * 16 + lnhi * 4 + r;
          out[(size_t)rowm * 512 + col] = acc[mf][nf][r] + bv;
        }
      }
    }
  }
}

// -------------------------------------------- KV[d][e] partials + Ksum[d]
// grid = 64 bh * 16 k-splits; 256 tokens per block; 4x4 register tile/thread;
// tk-blocked x4.
__global__ __launch_bounds__(256) void k_kv(const u16* __restrict__ kphi,
                                            const u16* __restrict__ vbuf,
                                            float* __restrict__ kvpart,
                                            float* __restrict__ kspart) {
  __shared__ __align__(16) float kf[16][64];
  __shared__ __align__(16) float vf[16][64];
  int bx = blockIdx.x;
  int bh = bx >> 4, ck = bx & 15;
  int tid = threadIdx.x;
  size_t base = ((size_t)bh * 4096 + ck * 256) * 64;
  float acc[4][4] = {};
  float ks[4] = {0.f, 0.f, 0.f, 0.f};
  int dq = tid >> 4, eq = tid & 15;
  int d0 = dq * 4, e0 = eq * 4;
  int half = tid >> 7;
  int t2 = tid & 127;
  int srow = t2 >> 3, sch = t2 & 7;

  for (int step = 0; step < 16; step++) {
    {
      const u16* src = (half ? vbuf : kphi) + base + (size_t)(step * 16 + srow) * 64 + sch * 8;
      s16x8 v8 = *(const s16x8*)src;
      float* dst = (half ? &vf[0][0] : &kf[0][0]) + srow * 64 + sch * 8;
      f32x4 lo = {bf2f((u16)v8[0]), bf2f((u16)v8[1]), bf2f((u16)v8[2]), bf2f((u16)v8[3])};
      f32x4 hi = {bf2f((u16)v8[4]), bf2f((u16)v8[5]), bf2f((u16)v8[6]), bf2f((u16)v8[7])};
      *(f32x4*)dst = lo;
      *(f32x4*)(dst + 4) = hi;
    }
    __syncthreads();
#pragma unroll
    for (int tkb = 0; tkb < 4; tkb++) {
      f32x4 kq[4], vq[4];
#pragma unroll
      for (int j = 0; j < 4; j++) {
        kq[j] = *(const f32x4*)&kf[tkb * 4 + j][d0];
        vq[j] = *(const f32x4*)&vf[tkb * 4 + j][e0];
      }
#pragma unroll
      for (int j = 0; j < 4; j++) {
#pragma unroll
        for (int i = 0; i < 4; i++)
#pragma unroll
          for (int l = 0; l < 4; l++) acc[i][l] += kq[j][i] * vq[j][l];
        if (eq == 0) {
#pragma unroll
          for (int i = 0; i < 4; i++) ks[i] += kq[j][i];
        }
      }
    }
    __syncthreads();
  }
  size_t pb = (size_t)(bh * 16 + ck) * 4096;
#pragma unroll
  for (int i = 0; i < 4; i++) {
    f32x4 oo = {acc[i][0], acc[i][1], acc[i][2], acc[i][3]};
    *(f32x4*)(kvpart + pb + (size_t)(d0 + i) * 64 + e0) = oo;
  }
  if (eq == 0) {
    f32x4 oo = {ks[0], ks[1], ks[2], ks[3]};
    *(f32x4*)(kspart + (size_t)(bh * 16 + ck) * 64 + d0) = oo;
  }
}

// --------------------- reduce partials -> KVt[e][d] bf16 (pre-swizzled) + Ksum
__global__ __launch_bounds__(256) void k_kvred(const float* __restrict__ kvpart,
                                               const float* __restrict__ kspart,
                                               u16* __restrict__ kvt_sw,
                                               float* __restrict__ ksum) {
  int bh = blockIdx.x;
  int tid = threadIdx.x;
  int e = tid >> 2, d0 = (tid & 3) * 16;
  size_t pb = (size_t)bh * 16 * 4096;
#pragma unroll
  for (int dd = 0; dd < 16; dd++) {
    int d = d0 + dd;
    float s = 0.f;
#pragma unroll
    for (int c = 0; c < 16; c++) s += kvpart[pb + (size_t)c * 4096 + d * 64 + e];
    int chs = (d >> 3) ^ (e & 7);
    kvt_sw[((size_t)bh * 64 + e) * 64 + chs * 8 + (d & 7)] = f2bf(s);
  }
  if (tid < 64) {
    float s = 0.f;
#pragma unroll
    for (int c = 0; c < 16; c++) s += kspart[(size_t)bh * 1024 + c * 64 + tid];
    ksum[bh * 64 + tid] = s;
  }
}

// ------------------------- y[tok][h*64+e] = (q_phi @ KV) / (q_phi . Ksum + eps)
__global__ __launch_bounds__(256, 2) void k_attnout(const u16* __restrict__ qphi,
                                                    const u16* __restrict__ kvt_sw,
                                                    const float* __restrict__ ksum,
                                                    u16* __restrict__ y) {
  __shared__ __align__(16) u16 qa[256 * 64];
  __shared__ __align__(16) u16 bb[64 * 64];
  __shared__ float ksl[64];
  __shared__ float rdnl[256];
  int bx = blockIdx.x;
  int bh = bx >> 4, tch = bx & 15;
  int b = bh >> 3, hh = bh & 7;
  int tid = threadIdx.x, w = tid >> 6, lane = tid & 63;
  int lnlo = lane & 15, lnhi = lane >> 4;
  size_t qbase = ((size_t)bh * 4096 + tch * 256) * 64;

#pragma unroll
  for (int i = 0; i < 8; i++) {
    int c = i * 256 + tid;
    int row = c >> 3, ch = c & 7;
    int gcol = (ch ^ (row & 7)) << 3;
    gload16(qphi + qbase + (size_t)row * 64 + gcol, &qa[c * 8]);
  }
#pragma unroll
  for (int i = 0; i < 2; i++) {
    int c = i * 256 + tid;
    gload16(kvt_sw + (size_t)bh * 4096 + c * 8, &bb[c * 8]);
  }
  if (tid < 64) ksl[tid] = ksum[bh * 64 + tid];
  __syncthreads();

  {
    float den = 0.f;
#pragma unroll
    for (int ch = 0; ch < 8; ch++) {
      s16x8 v8 = *(const s16x8*)&qa[tid * 64 + ((ch ^ (tid & 7)) << 3)];
#pragma unroll
      for (int j = 0; j < 8; j++) den += bf2f((u16)v8[j]) * ksl[ch * 8 + j];
    }
    rdnl[tid] = 1.f / (den + 1e-6f);
  }
  __syncthreads();

  f32x4 acc[4][4] = {};
#pragma unroll
  for (int kk = 0; kk < 2; kk++) {
    s16x8 af[4], bfr[4];
#pragma unroll
    for (int f = 0; f < 4; f++) {
      int ra = w * 64 + f * 16 + lnlo;
      int ca = (kk * 4 + lnhi) ^ (ra & 7);
      af[f] = *(const s16x8*)&qa[ra * 64 + ca * 8];
      int rb = f * 16 + lnlo;
      int cb = (kk * 4 + lnhi) ^ (rb & 7);
      bfr[f] = *(const s16x8*)&bb[rb * 64 + cb * 8];
    }
#pragma unroll
    for (int mf = 0; mf < 4; mf++)
#pragma unroll
      for (int nf = 0; nf < 4; nf++)
        acc[mf][nf] = __builtin_amdgcn_mfma_f32_16x16x32_bf16(af[mf], bfr[nf], acc[mf][nf], 0, 0, 0);
  }

  size_t yrow0 = (size_t)b * 4096 + tch * 256;
#pragma unroll
  for (int mf = 0; mf < 4; mf++) {
#pragma unroll
    for (int nf = 0; nf < 4; nf++) {
      int e = nf * 16 + lnlo;
#pragma unroll
      for (int r = 0; r < 4; r++) {
        int tl = w * 64 + mf * 16 + lnhi * 4 + r;
        float val = acc[mf][nf][r] * rdnl[tl];
        y[(yrow0 + tl) * 512 + hh * 64 + e] = f2bf(val);
      }
    }
  }
}

// ------------------------------------------------------------------ launch
#define OFF_XB     ((size_t)0)             // 33,554,432  (also aliased as Y)
#define OFF_WQKVT  ((size_t)33554432)      //  1,572,864
#define OFF_WOUTT  ((size_t)35127296)      //    524,288
#define OFF_QPHI   ((size_t)35651584)      // 33,554,432
#define OFF_KPHI   ((size_t)69206016)      // 33,554,432
#define OFF_VBUF   ((size_t)102760448)     // 33,554,432
#define OFF_KVPART ((size_t)136314880)     // 16,777,216
#define OFF_KSPART ((size_t)153092096)     //    262,144
#define OFF_KVT    ((size_t)153354240)     //    524,288
#define OFF_KSUM   ((size_t)153878528)     //     16,384

extern "C" void kernel_launch(void* const* d_in, const int* in_sizes, int n_in,
                              void* d_out, int out_size, void* d_ws, size_t ws_size,
                              hipStream_t stream) {
  const float* x    = (const float*)d_in[0];
  const float* Wqkv = (const float*)d_in[1];
  const float* Wout = (const float*)d_in[2];
  const float* bout = (const float*)d_in[3];
  float* out = (float*)d_out;
  char* ws = (char*)d_ws;

  u16* xb     = (u16*)(ws + OFF_XB);
  u16* y      = (u16*)(ws + OFF_XB);  // alias: xb dead after GEMM1
  u16* wqkvt  = (u16*)(ws + OFF_WQKVT);
  u16* woutt  = (u16*)(ws + OFF_WOUTT);
  u16* qphi   = (u16*)(ws + OFF_QPHI);
  u16* kphi   = (u16*)(ws + OFF_KPHI);
  u16* vbuf   = (u16*)(ws + OFF_VBUF);
  float* kvpart = (float*)(ws + OFF_KVPART);
  float* kspart = (float*)(ws + OFF_KSPART);
  u16* kvt_sw = (u16*)(ws + OFF_KVT);
  float* ksum = (float*)(ws + OFF_KSUM);

  k_conv_bf16<<<2048, 256, 0, stream>>>(x, xb, 16777216 / 8);
  k_transpose_bf16<<<(1536 / 64) * (512 / 64), 256, 0, stream>>>(Wqkv, wqkvt, 512, 1536);
  k_transpose_bf16<<<(512 / 64) * (512 / 64), 256, 0, stream>>>(Wout, woutt, 512, 512);

  // qkv = xb @ Wqkv (+ phi epilogue scatter). M-blocks=256, N-blocks=6 -> 1536
  k_gemm<0><<<1536, 256, 0, stream>>>(xb, wqkvt, 256, qphi, kphi, vbuf, nullptr, nullptr);
  k_kv<<<64 * 16, 256, 0, stream>>>(kphi, vbuf, kvpart, kspart);
  k_kvred<<<64, 256, 0, stream>>>(kvpart, kspart, kvt_sw, ksum);
  k_attnout<<<64 * 16, 256, 0, stream>>>(qphi, kvt_sw, ksum, y);
  // out = y @ Wout + b. M-blocks=256, N-blocks=2 -> 512
  k_gemm<1><<<512, 256, 0, stream>>>(y, woutt, 256, nullptr, nullptr, nullptr, out, bout);
}

// Round 7
// 184.902 us; speedup vs baseline: 1.0671x; 1.0628x over previous
//
#include <hip/hip_runtime.h>
#include <stdint.h>

typedef float    f32x4 __attribute__((ext_vector_type(4)));
typedef short    s16x8 __attribute__((ext_vector_type(8)));
typedef short    s16x4 __attribute__((ext_vector_type(4)));
typedef unsigned short u16;
typedef uint32_t u32;

#define DEVINL __device__ __forceinline__
#define CFENCE asm volatile("" ::: "memory")

DEVINL float bf2f(u16 u) { union { u32 i; float f; } x; x.i = ((u32)u) << 16; return x.f; }
DEVINL u16 f2bf(float f) {
  union { float f; u32 i; } x; x.f = f;
  u32 i = x.i;
  return (u16)((i + 0x7FFFu + ((i >> 16) & 1u)) >> 16);  // RNE
}

DEVINL void gload16(const void* g, void* l) {
  __builtin_amdgcn_global_load_lds((const __attribute__((address_space(1))) void*)g,
                                   (__attribute__((address_space(3))) void*)l,
                                   16, 0, 0);
}

// ---------------------------------------------------------------- conv x->bf16
__global__ __launch_bounds__(256) void k_conv_bf16(const float* __restrict__ x,
                                                   u16* __restrict__ xb, int n8) {
  int stride = gridDim.x * blockDim.x;
  for (int i = blockIdx.x * blockDim.x + threadIdx.x; i < n8; i += stride) {
    const f32x4* p = (const f32x4*)(x + (size_t)i * 8);
    f32x4 a = p[0], b = p[1];
    s16x8 o;
    o[0] = (short)f2bf(a[0]); o[1] = (short)f2bf(a[1]);
    o[2] = (short)f2bf(a[2]); o[3] = (short)f2bf(a[3]);
    o[4] = (short)f2bf(b[0]); o[5] = (short)f2bf(b[1]);
    o[6] = (short)f2bf(b[2]); o[7] = (short)f2bf(b[3]);
    *(s16x8*)(xb + (size_t)i * 8) = o;
  }
}

// ---------------------------------------------- W[K][N] fp32 -> Wt[N][K] bf16
__global__ __launch_bounds__(256) void k_transpose_bf16(const float* __restrict__ W,
                                                        u16* __restrict__ Wt, int K, int N) {
  __shared__ __align__(16) float t[64][65];
  int nb = N >> 6;
  int tn = blockIdx.x % nb, tk = blockIdx.x / nb;
  int n0 = tn << 6, k0 = tk << 6;
  int tid = threadIdx.x;
  int cr = tid >> 4, cc = (tid & 15) << 2;
#pragma unroll
  for (int i = 0; i < 4; i++) {
    int r = cr + (i << 4);
    f32x4 v = *(const f32x4*)(W + (size_t)(k0 + r) * N + n0 + cc);
    t[r][cc] = v[0]; t[r][cc + 1] = v[1]; t[r][cc + 2] = v[2]; t[r][cc + 3] = v[3];
  }
  __syncthreads();
#pragma unroll
  for (int i = 0; i < 4; i++) {
    int nn = cr + (i << 4);
    s16x4 o;
    o[0] = (short)f2bf(t[cc    ][nn]);
    o[1] = (short)f2bf(t[cc + 1][nn]);
    o[2] = (short)f2bf(t[cc + 2][nn]);
    o[3] = (short)f2bf(t[cc + 3][nn]);
    *(s16x4*)(Wt + (size_t)(n0 + nn) * K + k0 + cc) = o;
  }
}

// ------------------------------------------------------------------- GEMM
// r4 K-loop kept verbatim (best measured). NEW: EPI0 epilogue routes the
// scatter through a padded LDS transpose buffer so global stores become
// 16B/lane fully-coalesced (128B bursts) instead of 4x32B segments per inst,
// and the q/k/v select + phi hoist out (sec is block-uniform).
// EPI 1: out = val + bias, fp32 (already 64B segments; direct).
template <int EPI>
__global__ __launch_bounds__(512, 1) void k_gemm(
    const u16* __restrict__ A, const u16* __restrict__ Bt,
    int nbn,
    u16* __restrict__ qph, u16* __restrict__ kph, u16* __restrict__ vv,
    float* __restrict__ out, const float* __restrict__ bias) {
  __shared__ __align__(16) u16 lsA[3][256 * 32];
  __shared__ __align__(16) u16 lsB[3][256 * 32];

  int nwg = gridDim.x;
  int bx = blockIdx.x;
  int o = (bx & 7) * (nwg >> 3) + (bx >> 3);
  int bm = o / nbn, bn = o % nbn;
  int m0 = bm << 8, n0 = bn << 8;
  int tid = threadIdx.x;
  int w = tid >> 6, lane = tid & 63;
  int lnlo = lane & 15, lnhi = lane >> 4;
  int wr = w >> 2, wc = w & 3;

  const u16* gAp[2]; const u16* gBp[2]; int ldst[2];
#pragma unroll
  for (int i = 0; i < 2; i++) {
    int c = tid + i * 512;
    int row = c >> 2, ch = c & 3;
    int gch = ch ^ ((row >> 1) & 3);
    gAp[i] = A + (size_t)(m0 + row) * 512 + gch * 8;
    gBp[i] = Bt + (size_t)(n0 + row) * 512 + gch * 8;
    ldst[i] = c * 8;
  }

  int offA[8], offB[4];
#pragma unroll
  for (int f = 0; f < 8; f++) {
    int r = wr * 128 + f * 16 + lnlo;
    offA[f] = r * 32 + (lnhi ^ ((r >> 1) & 3)) * 8;
  }
#pragma unroll
  for (int f = 0; f < 4; f++) {
    int r = wc * 64 + f * 16 + lnlo;
    offB[f] = r * 32 + (lnhi ^ ((r >> 1) & 3)) * 8;
  }

  f32x4 acc[8][4] = {};

#pragma unroll
  for (int i = 0; i < 2; i++) gload16(gAp[i], &lsA[0][ldst[i]]);
#pragma unroll
  for (int i = 0; i < 2; i++) gload16(gBp[i], &lsB[0][ldst[i]]);
#pragma unroll
  for (int i = 0; i < 2; i++) gload16(gAp[i] + 32, &lsA[1][ldst[i]]);
#pragma unroll
  for (int i = 0; i < 2; i++) gload16(gBp[i] + 32, &lsB[1][ldst[i]]);
  asm volatile("s_waitcnt vmcnt(4)" ::: "memory");
  __builtin_amdgcn_s_barrier();

#pragma unroll
  for (int t = 0; t < 16; t++) {
    int buf = t % 3;
    const u16* La = &lsA[buf][0];
    const u16* Lb = &lsB[buf][0];
    int k2 = (t + 2) * 32;
    int b2 = (t + 2) % 3;

    s16x8 bf[4], af[4];
#pragma unroll
    for (int f = 0; f < 4; f++) bf[f] = *(const s16x8*)(Lb + offB[f]);
#pragma unroll
    for (int f = 0; f < 4; f++) af[f] = *(const s16x8*)(La + offA[f]);
    if (t < 14) {
#pragma unroll
      for (int i = 0; i < 2; i++) gload16(gAp[i] + k2, &lsA[b2][ldst[i]]);
    }
    __builtin_amdgcn_s_barrier();
    __builtin_amdgcn_s_setprio(1);
#pragma unroll
    for (int mf = 0; mf < 4; mf++)
#pragma unroll
      for (int nf = 0; nf < 4; nf++)
        acc[mf][nf] = __builtin_amdgcn_mfma_f32_16x16x32_bf16(af[mf], bf[nf], acc[mf][nf], 0, 0, 0);
    __builtin_amdgcn_s_setprio(0);
    __builtin_amdgcn_s_barrier();

    s16x8 af2[4];
#pragma unroll
    for (int f = 0; f < 4; f++) af2[f] = *(const s16x8*)(La + offA[4 + f]);
    if (t < 14) {
#pragma unroll
      for (int i = 0; i < 2; i++) gload16(gBp[i] + k2, &lsB[b2][ldst[i]]);
    }
    __builtin_amdgcn_s_barrier();
    __builtin_amdgcn_s_setprio(1);
#pragma unroll
    for (int mf = 0; mf < 4; mf++)
#pragma unroll
      for (int nf = 0; nf < 4; nf++)
        acc[4 + mf][nf] = __builtin_amdgcn_mfma_f32_16x16x32_bf16(af2[mf], bf[nf], acc[4 + mf][nf], 0, 0, 0);
    __builtin_amdgcn_s_setprio(0);
    if (t <= 13)      asm volatile("s_waitcnt vmcnt(4)" ::: "memory");
    else if (t == 14) asm volatile("s_waitcnt vmcnt(0)" ::: "memory");
    if (t < 15) __builtin_amdgcn_s_barrier();
  }

  if (EPI == 0) {
    // ---- LDS-transpose epilogue: coalesced scatter to [bh][tok][d] ----
    __syncthreads();                       // all K-loop LDS reads retired
    u16* ebuf = &lsA[0][0];                // 32 x 272 bf16 = 17.4 KB (alias ok)
    const int EROW = 272;                  // pad: row stride 544B -> bank +8
    int sec = n0 >> 9;                     // block-uniform (256-col tile)
    u16* dstE = (sec == 0) ? qph : ((sec == 1) ? kph : vv);
    bool isphi = (sec < 2);
    int erow = tid >> 4;                   // 0..31
    int ecol = (tid & 15) << 4;            // 0..240, 16 cols (32B) per thread
    int rowm = m0 + ((erow >> 4) << 7) + (erow & 15);  // + mf*16 added in loop
    int col = n0 + ecol;
    int hh = (col >> 6) & 7, dd = col & 63;
#pragma unroll
    for (int mf = 0; mf < 8; mf++) {
#pragma unroll
      for (int nf = 0; nf < 4; nf++)
#pragma unroll
        for (int r = 0; r < 4; r++) {
          float val = acc[mf][nf][r];
          if (isphi) val = (val > 0.f) ? (val + 1.f) : __expf(val);  // elu+1
          ebuf[(wr * 16 + lnhi * 4 + r) * EROW + wc * 64 + nf * 16 + lnlo] = f2bf(val);
        }
      __syncthreads();
      {
        int rm = rowm + mf * 16;
        int bidx = rm >> 12, tok = rm & 4095;
        size_t base = (((size_t)(bidx * 8 + hh) * 4096 + tok) << 6) + dd;
        s16x8 v0 = *(const s16x8*)&ebuf[erow * EROW + ecol];
        s16x8 v1 = *(const s16x8*)&ebuf[erow * EROW + ecol + 8];
        *(s16x8*)&dstE[base] = v0;
        *(s16x8*)&dstE[base + 8] = v1;
      }
      __syncthreads();
    }
  } else {
    int gmB = m0 + wr * 128;
    int gnB = n0 + wc * 64;
#pragma unroll
    for (int mf = 0; mf < 8; mf++) {
#pragma unroll
      for (int nf = 0; nf < 4; nf++) {
        int col = gnB + nf * 16 + lnlo;
        float bv = bias[col];
#pragma unroll
        for (int r = 0; r < 4; r++) {
          int rowm = gmB + mf * 16 + lnhi * 4 + r;
          out[(size_t)rowm * 512 + col] = acc[mf][nf][r] + bv;
        }
      }
    }
  }
}

// -------------------------------------------- KV[d][e] partials + Ksum[d]
__global__ __launch_bounds__(256) void k_kv(const u16* __restrict__ kphi,
                                            const u16* __restrict__ vbuf,
                                            float* __restrict__ kvpart,
                                            float* __restrict__ kspart) {
  __shared__ __align__(16) float kf[16][64];
  __shared__ __align__(16) float vf[16][64];
  int bx = blockIdx.x;
  int bh = bx >> 4, ck = bx & 15;
  int tid = threadIdx.x;
  size_t base = ((size_t)bh * 4096 + ck * 256) * 64;
  float acc[4][4] = {};
  float ks[4] = {0.f, 0.f, 0.f, 0.f};
  int dq = tid >> 4, eq = tid & 15;
  int d0 = dq * 4, e0 = eq * 4;
  int half = tid >> 7;
  int t2 = tid & 127;
  int srow = t2 >> 3, sch = t2 & 7;

  for (int step = 0; step < 16; step++) {
    {
      const u16* src = (half ? vbuf : kphi) + base + (size_t)(step * 16 + srow) * 64 + sch * 8;
      s16x8 v8 = *(const s16x8*)src;
      float* dst = (half ? &vf[0][0] : &kf[0][0]) + srow * 64 + sch * 8;
      f32x4 lo = {bf2f((u16)v8[0]), bf2f((u16)v8[1]), bf2f((u16)v8[2]), bf2f((u16)v8[3])};
      f32x4 hi = {bf2f((u16)v8[4]), bf2f((u16)v8[5]), bf2f((u16)v8[6]), bf2f((u16)v8[7])};
      *(f32x4*)dst = lo;
      *(f32x4*)(dst + 4) = hi;
    }
    __syncthreads();
#pragma unroll
    for (int tkb = 0; tkb < 4; tkb++) {
      f32x4 kq[4], vq[4];
#pragma unroll
      for (int j = 0; j < 4; j++) {
        kq[j] = *(const f32x4*)&kf[tkb * 4 + j][d0];
        vq[j] = *(const f32x4*)&vf[tkb * 4 + j][e0];
      }
#pragma unroll
      for (int j = 0; j < 4; j++) {
#pragma unroll
        for (int i = 0; i < 4; i++)
#pragma unroll
          for (int l = 0; l < 4; l++) acc[i][l] += kq[j][i] * vq[j][l];
        if (eq == 0) {
#pragma unroll
          for (int i = 0; i < 4; i++) ks[i] += kq[j][i];
        }
      }
    }
    __syncthreads();
  }
  size_t pb = (size_t)(bh * 16 + ck) * 4096;
#pragma unroll
  for (int i = 0; i < 4; i++) {
    f32x4 oo = {acc[i][0], acc[i][1], acc[i][2], acc[i][3]};
    *(f32x4*)(kvpart + pb + (size_t)(d0 + i) * 64 + e0) = oo;
  }
  if (eq == 0) {
    f32x4 oo = {ks[0], ks[1], ks[2], ks[3]};
    *(f32x4*)(kspart + (size_t)(bh * 16 + ck) * 64 + d0) = oo;
  }
}

// --------------------- reduce partials -> KVt[e][d] bf16 (pre-swizzled) + Ksum
__global__ __launch_bounds__(256) void k_kvred(const float* __restrict__ kvpart,
                                               const float* __restrict__ kspart,
                                               u16* __restrict__ kvt_sw,
                                               float* __restrict__ ksum) {
  int bh = blockIdx.x;
  int tid = threadIdx.x;
  int e = tid >> 2, d0 = (tid & 3) * 16;
  size_t pb = (size_t)bh * 16 * 4096;
#pragma unroll
  for (int dd = 0; dd < 16; dd++) {
    int d = d0 + dd;
    float s = 0.f;
#pragma unroll
    for (int c = 0; c < 16; c++) s += kvpart[pb + (size_t)c * 4096 + d * 64 + e];
    int chs = (d >> 3) ^ (e & 7);
    kvt_sw[((size_t)bh * 64 + e) * 64 + chs * 8 + (d & 7)] = f2bf(s);
  }
  if (tid < 64) {
    float s = 0.f;
#pragma unroll
    for (int c = 0; c < 16; c++) s += kspart[(size_t)bh * 1024 + c * 64 + tid];
    ksum[bh * 64 + tid] = s;
  }
}

// ------------------------- y[tok][h*64+e] = (q_phi @ KV) / (q_phi . Ksum + eps)
// NEW: wave-private LDS-transpose epilogue (reuses the wave's own dead qa
// region, no barriers) -> y stores are 16B/lane coalesced.
__global__ __launch_bounds__(256, 2) void k_attnout(const u16* __restrict__ qphi,
                                                    const u16* __restrict__ kvt_sw,
                                                    const float* __restrict__ ksum,
                                                    u16* __restrict__ y) {
  __shared__ __align__(16) u16 qa[256 * 64];
  __shared__ __align__(16) u16 bb[64 * 64];
  __shared__ float ksl[64];
  __shared__ float rdnl[256];
  int bx = blockIdx.x;
  int bh = bx >> 4, tch = bx & 15;
  int b = bh >> 3, hh = bh & 7;
  int tid = threadIdx.x, w = tid >> 6, lane = tid & 63;
  int lnlo = lane & 15, lnhi = lane >> 4;
  size_t qbase = ((size_t)bh * 4096 + tch * 256) * 64;

#pragma unroll
  for (int i = 0; i < 8; i++) {
    int c = i * 256 + tid;
    int row = c >> 3, ch = c & 7;
    int gcol = (ch ^ (row & 7)) << 3;
    gload16(qphi + qbase + (size_t)row * 64 + gcol, &qa[c * 8]);
  }
#pragma unroll
  for (int i = 0; i < 2; i++) {
    int c = i * 256 + tid;
    gload16(kvt_sw + (size_t)bh * 4096 + c * 8, &bb[c * 8]);
  }
  if (tid < 64) ksl[tid] = ksum[bh * 64 + tid];
  __syncthreads();

  {
    float den = 0.f;
#pragma unroll
    for (int ch = 0; ch < 8; ch++) {
      s16x8 v8 = *(const s16x8*)&qa[tid * 64 + ((ch ^ (tid & 7)) << 3)];
#pragma unroll
      for (int j = 0; j < 8; j++) den += bf2f((u16)v8[j]) * ksl[ch * 8 + j];
    }
    rdnl[tid] = 1.f / (den + 1e-6f);
  }
  __syncthreads();

  f32x4 acc[4][4] = {};
#pragma unroll
  for (int kk = 0; kk < 2; kk++) {
    s16x8 af[4], bfr[4];
#pragma unroll
    for (int f = 0; f < 4; f++) {
      int ra = w * 64 + f * 16 + lnlo;
      int ca = (kk * 4 + lnhi) ^ (ra & 7);
      af[f] = *(const s16x8*)&qa[ra * 64 + ca * 8];
      int rb = f * 16 + lnlo;
      int cb = (kk * 4 + lnhi) ^ (rb & 7);
      bfr[f] = *(const s16x8*)&bb[rb * 64 + cb * 8];
    }
#pragma unroll
    for (int mf = 0; mf < 4; mf++)
#pragma unroll
      for (int nf = 0; nf < 4; nf++)
        acc[mf][nf] = __builtin_amdgcn_mfma_f32_16x16x32_bf16(af[mf], bfr[nf], acc[mf][nf], 0, 0, 0);
  }

  // wave-private transpose epilogue; ebuf aliases this wave's own qa region
  // (its reads are retired: this wave's MFMAs consumed them).
  u16* ebuf = &qa[w * 4096];
  const int AROW = 72;                       // pad: 144B row stride
  int erow = lane >> 2, echunk = (lane & 3) << 4;  // 16 rows x 4 chunks(16 col)
  size_t yrow0 = (size_t)b * 4096 + tch * 256;
#pragma unroll
  for (int mf = 0; mf < 4; mf++) {
#pragma unroll
    for (int nf = 0; nf < 4; nf++)
#pragma unroll
      for (int r = 0; r < 4; r++) {
        int tl = w * 64 + mf * 16 + lnhi * 4 + r;
        float val = acc[mf][nf][r] * rdnl[tl];
        ebuf[(lnhi * 4 + r) * AROW + nf * 16 + lnlo] = f2bf(val);
      }
    asm volatile("s_waitcnt lgkmcnt(0)" ::: "memory");
    {
      int tok = w * 64 + mf * 16 + erow;
      size_t dst = (yrow0 + tok) * 512 + hh * 64 + echunk;
      s16x8 v0 = *(const s16x8*)&ebuf[erow * AROW + echunk];
      s16x8 v1 = *(const s16x8*)&ebuf[erow * AROW + echunk + 8];
      *(s16x8*)&y[dst] = v0;
      *(s16x8*)&y[dst + 8] = v1;
    }
    asm volatile("s_waitcnt lgkmcnt(0)" ::: "memory");
  }
}

// ------------------------------------------------------------------ launch
#define OFF_XB     ((size_t)0)             // 33,554,432  (also aliased as Y)
#define OFF_WQKVT  ((size_t)33554432)      //  1,572,864
#define OFF_WOUTT  ((size_t)35127296)      //    524,288
#define OFF_QPHI   ((size_t)35651584)      // 33,554,432
#define OFF_KPHI   ((size_t)69206016)      // 33,554,432
#define OFF_VBUF   ((size_t)102760448)     // 33,554,432
#define OFF_KVPART ((size_t)136314880)     // 16,777,216
#define OFF_KSPART ((size_t)153092096)     //    262,144
#define OFF_KVT    ((size_t)153354240)     //    524,288
#define OFF_KSUM   ((size_t)153878528)     //     16,384

extern "C" void kernel_launch(void* const* d_in, const int* in_sizes, int n_in,
                              void* d_out, int out_size, void* d_ws, size_t ws_size,
                              hipStream_t stream) {
  const float* x    = (const float*)d_in[0];
  const float* Wqkv = (const float*)d_in[1];
  const float* Wout = (const float*)d_in[2];
  const float* bout = (const float*)d_in[3];
  float* out = (float*)d_out;
  char* ws = (char*)d_ws;

  u16* xb     = (u16*)(ws + OFF_XB);
  u16* y      = (u16*)(ws + OFF_XB);  // alias: xb dead after GEMM1
  u16* wqkvt  = (u16*)(ws + OFF_WQKVT);
  u16* woutt  = (u16*)(ws + OFF_WOUTT);
  u16* qphi   = (u16*)(ws + OFF_QPHI);
  u16* kphi   = (u16*)(ws + OFF_KPHI);
  u16* vbuf   = (u16*)(ws + OFF_VBUF);
  float* kvpart = (float*)(ws + OFF_KVPART);
  float* kspart = (float*)(ws + OFF_KSPART);
  u16* kvt_sw = (u16*)(ws + OFF_KVT);
  float* ksum = (float*)(ws + OFF_KSUM);

  k_conv_bf16<<<2048, 256, 0, stream>>>(x, xb, 16777216 / 8);
  k_transpose_bf16<<<(1536 / 64) * (512 / 64), 256, 0, stream>>>(Wqkv, wqkvt, 512, 1536);
  k_transpose_bf16<<<(512 / 64) * (512 / 64), 256, 0, stream>>>(Wout, woutt, 512, 512);

  // qkv = xb @ Wqkv (+ phi epilogue, coalesced scatter). 128x6 = 768 blocks
  k_gemm<0><<<768, 512, 0, stream>>>(xb, wqkvt, 6, qphi, kphi, vbuf, nullptr, nullptr);
  k_kv<<<64 * 16, 256, 0, stream>>>(kphi, vbuf, kvpart, kspart);
  k_kvred<<<64, 256, 0, stream>>>(kvpart, kspart, kvt_sw, ksum);
  k_attnout<<<64 * 16, 256, 0, stream>>>(qphi, kvt_sw, ksum, y);
  // out = y @ Wout + b. 128x2 = 256 blocks
  k_gemm<1><<<256, 512, 0, stream>>>(y, woutt, 2, nullptr, nullptr, nullptr, out, bout);
}

// Round 8
// 159.325 us; speedup vs baseline: 1.2384x; 1.1605x over previous
//
#include <hip/hip_runtime.h>
#include <stdint.h>

typedef float    f32x4 __attribute__((ext_vector_type(4)));
typedef short    s16x8 __attribute__((ext_vector_type(8)));
typedef short    s16x4 __attribute__((ext_vector_type(4)));
typedef unsigned short u16;
typedef uint32_t u32;

#define DEVINL __device__ __forceinline__

DEVINL float bf2f(u16 u) { union { u32 i; float f; } x; x.i = ((u32)u) << 16; return x.f; }
DEVINL u16 f2bf(float f) {
  union { float f; u32 i; } x; x.f = f;
  u32 i = x.i;
  return (u16)((i + 0x7FFFu + ((i >> 16) & 1u)) >> 16);  // RNE
}

DEVINL void gload16(const void* g, void* l) {
  __builtin_amdgcn_global_load_lds((const __attribute__((address_space(1))) void*)g,
                                   (__attribute__((address_space(3))) void*)l,
                                   16, 0, 0);
}

// --------------------------- prep: conv x->bf16 + both weight transposes
// One launch (3 graph nodes -> 1). blocks [0,2048): conv; [2048,2240): Wqkv^T;
// [2240,2304): Wout^T.
__global__ __launch_bounds__(256) void k_prep(const float* __restrict__ x,
                                              u16* __restrict__ xb,
                                              const float* __restrict__ Wqkv,
                                              u16* __restrict__ wqkvt,
                                              const float* __restrict__ Wout,
                                              u16* __restrict__ woutt) {
  __shared__ __align__(16) float t[64][65];
  int b = blockIdx.x;
  int tid = threadIdx.x;
  if (b < 2048) {
    const int n8 = 2097152;
    int stride = 2048 * 256;
    for (int i = b * 256 + tid; i < n8; i += stride) {
      const f32x4* p = (const f32x4*)(x + (size_t)i * 8);
      f32x4 a = p[0], c = p[1];
      s16x8 o;
      o[0] = (short)f2bf(a[0]); o[1] = (short)f2bf(a[1]);
      o[2] = (short)f2bf(a[2]); o[3] = (short)f2bf(a[3]);
      o[4] = (short)f2bf(c[0]); o[5] = (short)f2bf(c[1]);
      o[6] = (short)f2bf(c[2]); o[7] = (short)f2bf(c[3]);
      *(s16x8*)(xb + (size_t)i * 8) = o;
    }
    return;
  }
  const float* W; u16* Wt; int K, N, tb;
  if (b < 2048 + 192) { W = Wqkv; Wt = wqkvt; K = 512; N = 1536; tb = b - 2048; }
  else               { W = Wout; Wt = woutt; K = 512; N = 512;  tb = b - 2240; }
  int nb = N >> 6;
  int tn = tb % nb, tk = tb / nb;
  int n0 = tn << 6, k0 = tk << 6;
  int cr = tid >> 4, cc = (tid & 15) << 2;
#pragma unroll
  for (int i = 0; i < 4; i++) {
    int r = cr + (i << 4);
    f32x4 v = *(const f32x4*)(W + (size_t)(k0 + r) * N + n0 + cc);
    t[r][cc] = v[0]; t[r][cc + 1] = v[1]; t[r][cc + 2] = v[2]; t[r][cc + 3] = v[3];
  }
  __syncthreads();
#pragma unroll
  for (int i = 0; i < 4; i++) {
    int nn = cr + (i << 4);
    s16x4 o;
    o[0] = (short)f2bf(t[cc    ][nn]);
    o[1] = (short)f2bf(t[cc + 1][nn]);
    o[2] = (short)f2bf(t[cc + 2][nn]);
    o[3] = (short)f2bf(t[cc + 3][nn]);
    *(s16x4*)(Wt + (size_t)(n0 + nn) * K + k0 + cc) = o;
  }
}

// ------------------------------------------------------------------- GEMM
// r4 K-loop verbatim (best measured: 73.5us). EPI0 epilogue:
//   sec 0 (q): r4 direct scalar scatter to qphi[bh][tok][d] (+phi)
//   sec 1 (k): transposed 8B stores to kphiT[bh][d][tok] (+phi)
//   sec 2 (v): transposed 8B stores to vT[bh][d][tok]
// (4 consecutive-tok acc values -> one s16x4 store; 32 insts vs 128.)
// EPI 1: out = val + bias, fp32 direct.
template <int EPI>
__global__ __launch_bounds__(512, 1) void k_gemm(
    const u16* __restrict__ A, const u16* __restrict__ Bt,
    int nbn,
    u16* __restrict__ qph, u16* __restrict__ kphT, u16* __restrict__ vT,
    float* __restrict__ out, const float* __restrict__ bias) {
  __shared__ __align__(16) u16 lsA[3][256 * 32];
  __shared__ __align__(16) u16 lsB[3][256 * 32];

  int nwg = gridDim.x;
  int bx = blockIdx.x;
  int o = (bx & 7) * (nwg >> 3) + (bx >> 3);
  int bm = o / nbn, bn = o % nbn;
  int m0 = bm << 8, n0 = bn << 8;
  int tid = threadIdx.x;
  int w = tid >> 6, lane = tid & 63;
  int lnlo = lane & 15, lnhi = lane >> 4;
  int wr = w >> 2, wc = w & 3;

  const u16* gAp[2]; const u16* gBp[2]; int ldst[2];
#pragma unroll
  for (int i = 0; i < 2; i++) {
    int c = tid + i * 512;
    int row = c >> 2, ch = c & 3;
    int gch = ch ^ ((row >> 1) & 3);
    gAp[i] = A + (size_t)(m0 + row) * 512 + gch * 8;
    gBp[i] = Bt + (size_t)(n0 + row) * 512 + gch * 8;
    ldst[i] = c * 8;
  }

  int offA[8], offB[4];
#pragma unroll
  for (int f = 0; f < 8; f++) {
    int r = wr * 128 + f * 16 + lnlo;
    offA[f] = r * 32 + (lnhi ^ ((r >> 1) & 3)) * 8;
  }
#pragma unroll
  for (int f = 0; f < 4; f++) {
    int r = wc * 64 + f * 16 + lnlo;
    offB[f] = r * 32 + (lnhi ^ ((r >> 1) & 3)) * 8;
  }

  f32x4 acc[8][4] = {};

#pragma unroll
  for (int i = 0; i < 2; i++) gload16(gAp[i], &lsA[0][ldst[i]]);
#pragma unroll
  for (int i = 0; i < 2; i++) gload16(gBp[i], &lsB[0][ldst[i]]);
#pragma unroll
  for (int i = 0; i < 2; i++) gload16(gAp[i] + 32, &lsA[1][ldst[i]]);
#pragma unroll
  for (int i = 0; i < 2; i++) gload16(gBp[i] + 32, &lsB[1][ldst[i]]);
  asm volatile("s_waitcnt vmcnt(4)" ::: "memory");
  __builtin_amdgcn_s_barrier();

#pragma unroll
  for (int t = 0; t < 16; t++) {
    int buf = t % 3;
    const u16* La = &lsA[buf][0];
    const u16* Lb = &lsB[buf][0];
    int k2 = (t + 2) * 32;
    int b2 = (t + 2) % 3;

    s16x8 bf[4], af[4];
#pragma unroll
    for (int f = 0; f < 4; f++) bf[f] = *(const s16x8*)(Lb + offB[f]);
#pragma unroll
    for (int f = 0; f < 4; f++) af[f] = *(const s16x8*)(La + offA[f]);
    if (t < 14) {
#pragma unroll
      for (int i = 0; i < 2; i++) gload16(gAp[i] + k2, &lsA[b2][ldst[i]]);
    }
    __builtin_amdgcn_s_barrier();
    __builtin_amdgcn_s_setprio(1);
#pragma unroll
    for (int mf = 0; mf < 4; mf++)
#pragma unroll
      for (int nf = 0; nf < 4; nf++)
        acc[mf][nf] = __builtin_amdgcn_mfma_f32_16x16x32_bf16(af[mf], bf[nf], acc[mf][nf], 0, 0, 0);
    __builtin_amdgcn_s_setprio(0);
    __builtin_amdgcn_s_barrier();

    s16x8 af2[4];
#pragma unroll
    for (int f = 0; f < 4; f++) af2[f] = *(const s16x8*)(La + offA[4 + f]);
    if (t < 14) {
#pragma unroll
      for (int i = 0; i < 2; i++) gload16(gBp[i] + k2, &lsB[b2][ldst[i]]);
    }
    __builtin_amdgcn_s_barrier();
    __builtin_amdgcn_s_setprio(1);
#pragma unroll
    for (int mf = 0; mf < 4; mf++)
#pragma unroll
      for (int nf = 0; nf < 4; nf++)
        acc[4 + mf][nf] = __builtin_amdgcn_mfma_f32_16x16x32_bf16(af2[mf], bf[nf], acc[4 + mf][nf], 0, 0, 0);
    __builtin_amdgcn_s_setprio(0);
    if (t <= 13)      asm volatile("s_waitcnt vmcnt(4)" ::: "memory");
    else if (t == 14) asm volatile("s_waitcnt vmcnt(0)" ::: "memory");
    if (t < 15) __builtin_amdgcn_s_barrier();
  }

  int gmB = m0 + wr * 128;
  int gnB = n0 + wc * 64;
  if (EPI == 0) {
    int sec = n0 >> 9;                       // block-uniform (256-col tile)
    if (sec == 0) {
#pragma unroll
      for (int mf = 0; mf < 8; mf++) {
#pragma unroll
        for (int nf = 0; nf < 4; nf++) {
          int col = gnB + nf * 16 + lnlo;
          int hh = (col >> 6) & 7;
          int dd = col & 63;
#pragma unroll
          for (int r = 0; r < 4; r++) {
            int rowm = gmB + mf * 16 + lnhi * 4 + r;
            float val = acc[mf][nf][r];
            val = (val > 0.f) ? (val + 1.f) : __expf(val);  // elu+1
            int bidx = rowm >> 12, tok = rowm & 4095;
            qph[(((size_t)(bidx * 8 + hh) * 4096 + tok) << 6) + dd] = f2bf(val);
          }
        }
      }
    } else {
      u16* dstT = (sec == 1) ? kphT : vT;    // [bh][d=64][n=4096]
      bool isphi = (sec == 1);
#pragma unroll
      for (int mf = 0; mf < 8; mf++) {
        int rowm = gmB + mf * 16 + lnhi * 4;
        int bidx = rowm >> 12, tok = rowm & 4095;
#pragma unroll
        for (int nf = 0; nf < 4; nf++) {
          int col = gnB + nf * 16 + lnlo;
          int hh = (col >> 6) & 7;
          int dd = col & 63;
          s16x4 o4;
#pragma unroll
          for (int r = 0; r < 4; r++) {
            float val = acc[mf][nf][r];
            if (isphi) val = (val > 0.f) ? (val + 1.f) : __expf(val);
            o4[r] = (short)f2bf(val);
          }
          *(s16x4*)&dstT[((size_t)(bidx * 8 + hh) * 64 + dd) * 4096 + tok] = o4;
        }
      }
    }
  } else {
#pragma unroll
    for (int mf = 0; mf < 8; mf++) {
#pragma unroll
      for (int nf = 0; nf < 4; nf++) {
        int col = gnB + nf * 16 + lnlo;
        float bv = bias[col];
#pragma unroll
        for (int r = 0; r < 4; r++) {
          int rowm = gmB + mf * 16 + lnhi * 4 + r;
          out[(size_t)rowm * 512 + col] = acc[mf][nf][r] + bv;
        }
      }
    }
  }
}

// -------------------------------------------- KV partials via MFMA + Ksum
// grid = 64 bh * 16 K-chunks(256 toks). C[d=64][e=64] = kphiT @ vT^T over
// the chunk. One-shot swizzled LDS staging (32 chunks/row, ch^(row&31)),
// proven k_gemm fragment pattern. Ksum = LDS row-sums (swizzle-invariant).
__global__ __launch_bounds__(256, 2) void k_kv(const u16* __restrict__ kphT,
                                               const u16* __restrict__ vT,
                                               float* __restrict__ kvpart,
                                               float* __restrict__ kspart) {
  __shared__ __align__(16) u16 lsK[64 * 256];   // 32 KB
  __shared__ __align__(16) u16 lsV[64 * 256];   // 32 KB
  __shared__ float red[4][64];
  int bx = blockIdx.x;
  int bh = bx >> 4, ck = bx & 15;
  int tid = threadIdx.x, w = tid >> 6, lane = tid & 63;
  int lnlo = lane & 15, lnhi = lane >> 4;
  size_t gbase = (size_t)bh * 64 * 4096 + ck * 256;

#pragma unroll
  for (int i = 0; i < 8; i++) {
    int c = tid + i * 256;
    int row = c >> 5, ch = c & 31;
    int gch = ch ^ (row & 31);
    gload16(kphT + gbase + (size_t)row * 4096 + gch * 8, &lsK[c * 8]);
  }
#pragma unroll
  for (int i = 0; i < 8; i++) {
    int c = tid + i * 256;
    int row = c >> 5, ch = c & 31;
    int gch = ch ^ (row & 31);
    gload16(vT + gbase + (size_t)row * 4096 + gch * 8, &lsV[c * 8]);
  }
  asm volatile("s_waitcnt vmcnt(0)" ::: "memory");
  __builtin_amdgcn_s_barrier();

  // MFMA: wave w owns e-columns w*16..w*16+15.
  f32x4 acc[4] = {{0.f, 0.f, 0.f, 0.f}, {0.f, 0.f, 0.f, 0.f},
                  {0.f, 0.f, 0.f, 0.f}, {0.f, 0.f, 0.f, 0.f}};
  int rb = w * 16 + lnlo;
#pragma unroll
  for (int kk = 0; kk < 8; kk++) {
    s16x8 bfr = *(const s16x8*)&lsV[rb * 256 + ((kk * 4 + lnhi) ^ (rb & 31)) * 8];
#pragma unroll
    for (int mf = 0; mf < 4; mf++) {
      int ra = mf * 16 + lnlo;
      s16x8 af = *(const s16x8*)&lsK[ra * 256 + ((kk * 4 + lnhi) ^ (ra & 31)) * 8];
      acc[mf] = __builtin_amdgcn_mfma_f32_16x16x32_bf16(af, bfr, acc[mf], 0, 0, 0);
    }
  }

  // Ksum: thread (d = tid&63, q = tid>>6) sums 8 chunks of row d.
  {
    int d = tid & 63, q = tid >> 6;
    float s = 0.f;
#pragma unroll
    for (int j = 0; j < 8; j++) {
      s16x8 v8 = *(const s16x8*)&lsK[d * 256 + (q * 8 + j) * 8];
#pragma unroll
      for (int e = 0; e < 8; e++) s += bf2f((u16)v8[e]);
    }
    red[q][d] = s;
  }
  __syncthreads();

  size_t pb = (size_t)(bh * 16 + ck) * 4096;
#pragma unroll
  for (int mf = 0; mf < 4; mf++)
#pragma unroll
    for (int r = 0; r < 4; r++)
      kvpart[pb + (size_t)(mf * 16 + lnhi * 4 + r) * 64 + (w * 16 + lnlo)] = acc[mf][r];
  if (tid < 64)
    kspart[(size_t)(bh * 16 + ck) * 64 + tid] =
        red[0][tid] + red[1][tid] + red[2][tid] + red[3][tid];
}

// --------------------- reduce partials -> KVt[e][d] bf16 (pre-swizzled) + Ksum
__global__ __launch_bounds__(256) void k_kvred(const float* __restrict__ kvpart,
                                               const float* __restrict__ kspart,
                                               u16* __restrict__ kvt_sw,
                                               float* __restrict__ ksum) {
  int bh = blockIdx.x;
  int tid = threadIdx.x;
  int e = tid >> 2, d0 = (tid & 3) * 16;
  size_t pb = (size_t)bh * 16 * 4096;
#pragma unroll
  for (int dd = 0; dd < 16; dd++) {
    int d = d0 + dd;
    float s = 0.f;
#pragma unroll
    for (int c = 0; c < 16; c++) s += kvpart[pb + (size_t)c * 4096 + d * 64 + e];
    int chs = (d >> 3) ^ (e & 7);
    kvt_sw[((size_t)bh * 64 + e) * 64 + chs * 8 + (d & 7)] = f2bf(s);
  }
  if (tid < 64) {
    float s = 0.f;
#pragma unroll
    for (int c = 0; c < 16; c++) s += kspart[(size_t)bh * 1024 + c * 64 + tid];
    ksum[bh * 64 + tid] = s;
  }
}

// ------------------------- y[tok][h*64+e] = (q_phi @ KV) / (q_phi . Ksum + eps)
__global__ __launch_bounds__(256, 2) void k_attnout(const u16* __restrict__ qphi,
                                                    const u16* __restrict__ kvt_sw,
                                                    const float* __restrict__ ksum,
                                                    u16* __restrict__ y) {
  __shared__ __align__(16) u16 qa[256 * 64];
  __shared__ __align__(16) u16 bb[64 * 64];
  __shared__ float ksl[64];
  __shared__ float rdnl[256];
  int bx = blockIdx.x;
  int bh = bx >> 4, tch = bx & 15;
  int b = bh >> 3, hh = bh & 7;
  int tid = threadIdx.x, w = tid >> 6, lane = tid & 63;
  int lnlo = lane & 15, lnhi = lane >> 4;
  size_t qbase = ((size_t)bh * 4096 + tch * 256) * 64;

#pragma unroll
  for (int i = 0; i < 8; i++) {
    int c = i * 256 + tid;
    int row = c >> 3, ch = c & 7;
    int gcol = (ch ^ (row & 7)) << 3;
    gload16(qphi + qbase + (size_t)row * 64 + gcol, &qa[c * 8]);
  }
#pragma unroll
  for (int i = 0; i < 2; i++) {
    int c = i * 256 + tid;
    gload16(kvt_sw + (size_t)bh * 4096 + c * 8, &bb[c * 8]);
  }
  if (tid < 64) ksl[tid] = ksum[bh * 64 + tid];
  __syncthreads();

  {
    float den = 0.f;
#pragma unroll
    for (int ch = 0; ch < 8; ch++) {
      s16x8 v8 = *(const s16x8*)&qa[tid * 64 + ((ch ^ (tid & 7)) << 3)];
#pragma unroll
      for (int j = 0; j < 8; j++) den += bf2f((u16)v8[j]) * ksl[ch * 8 + j];
    }
    rdnl[tid] = 1.f / (den + 1e-6f);
  }
  __syncthreads();

  f32x4 acc[4][4] = {};
#pragma unroll
  for (int kk = 0; kk < 2; kk++) {
    s16x8 af[4], bfr[4];
#pragma unroll
    for (int f = 0; f < 4; f++) {
      int ra = w * 64 + f * 16 + lnlo;
      int ca = (kk * 4 + lnhi) ^ (ra & 7);
      af[f] = *(const s16x8*)&qa[ra * 64 + ca * 8];
      int rb = f * 16 + lnlo;
      int cb = (kk * 4 + lnhi) ^ (rb & 7);
      bfr[f] = *(const s16x8*)&bb[rb * 64 + cb * 8];
    }
#pragma unroll
    for (int mf = 0; mf < 4; mf++)
#pragma unroll
      for (int nf = 0; nf < 4; nf++)
        acc[mf][nf] = __builtin_amdgcn_mfma_f32_16x16x32_bf16(af[mf], bfr[nf], acc[mf][nf], 0, 0, 0);
  }

  size_t yrow0 = (size_t)b * 4096 + tch * 256;
#pragma unroll
  for (int mf = 0; mf < 4; mf++) {
#pragma unroll
    for (int nf = 0; nf < 4; nf++) {
      int e = nf * 16 + lnlo;
#pragma unroll
      for (int r = 0; r < 4; r++) {
        int tl = w * 64 + mf * 16 + lnhi * 4 + r;
        float val = acc[mf][nf][r] * rdnl[tl];
        y[(yrow0 + tl) * 512 + hh * 64 + e] = f2bf(val);
      }
    }
  }
}

// ------------------------------------------------------------------ launch
#define OFF_XB     ((size_t)0)             // 33,554,432  (also aliased as Y)
#define OFF_WQKVT  ((size_t)33554432)      //  1,572,864
#define OFF_WOUTT  ((size_t)35127296)      //    524,288
#define OFF_QPHI   ((size_t)35651584)      // 33,554,432
#define OFF_KPHI   ((size_t)69206016)      // 33,554,432  (kphiT [bh][64][4096])
#define OFF_VBUF   ((size_t)102760448)     // 33,554,432  (vT    [bh][64][4096])
#define OFF_KVPART ((size_t)136314880)     // 16,777,216
#define OFF_KSPART ((size_t)153092096)     //    262,144
#define OFF_KVT    ((size_t)153354240)     //    524,288
#define OFF_KSUM   ((size_t)153878528)     //     16,384

extern "C" void kernel_launch(void* const* d_in, const int* in_sizes, int n_in,
                              void* d_out, int out_size, void* d_ws, size_t ws_size,
                              hipStream_t stream) {
  const float* x    = (const float*)d_in[0];
  const float* Wqkv = (const float*)d_in[1];
  const float* Wout = (const float*)d_in[2];
  const float* bout = (const float*)d_in[3];
  float* out = (float*)d_out;
  char* ws = (char*)d_ws;

  u16* xb     = (u16*)(ws + OFF_XB);
  u16* y      = (u16*)(ws + OFF_XB);  // alias: xb dead after GEMM1
  u16* wqkvt  = (u16*)(ws + OFF_WQKVT);
  u16* woutt  = (u16*)(ws + OFF_WOUTT);
  u16* qphi   = (u16*)(ws + OFF_QPHI);
  u16* kphT   = (u16*)(ws + OFF_KPHI);
  u16* vT     = (u16*)(ws + OFF_VBUF);
  float* kvpart = (float*)(ws + OFF_KVPART);
  float* kspart = (float*)(ws + OFF_KSPART);
  u16* kvt_sw = (u16*)(ws + OFF_KVT);
  float* ksum = (float*)(ws + OFF_KSUM);

  k_prep<<<2304, 256, 0, stream>>>(x, xb, Wqkv, wqkvt, Wout, woutt);

  // qkv = xb @ Wqkv (+ phi epilogue; q direct, k/v transposed). 128x6 = 768
  k_gemm<0><<<768, 512, 0, stream>>>(xb, wqkvt, 6, qphi, kphT, vT, nullptr, nullptr);
  k_kv<<<64 * 16, 256, 0, stream>>>(kphT, vT, kvpart, kspart);
  k_kvred<<<64, 256, 0, stream>>>(kvpart, kspart, kvt_sw, ksum);
  k_attnout<<<64 * 16, 256, 0, stream>>>(qphi, kvt_sw, ksum, y);
  // out = y @ Wout + b. 128x2 = 256 blocks
  k_gemm<1><<<256, 512, 0, stream>>>(y, woutt, 2, nullptr, nullptr, nullptr, out, bout);
}